// Round 3
// baseline (429.641 us; speedup 1.0000x reference)
//
#include <hip/hip_runtime.h>
#include <hip/hip_fp16.h>
#include <cstdint>
#include <cstddef>

// QLinear: per-token int8 quant -> int8 GEMM (MFMA 32x32x32 i8) -> dequant+bias
// M=8192, K=4096, N=4096.
//
// R3 changes vs R2 (gemm 180us, MfmaUtil 33%):
//  - K-loop split into 2 template-style sub-phases per K-tile:
//      {ds_read 12 frags; issue 4 global_load_lds (half of next tile);
//       raw s_barrier; setprio(1); 16 MFMA; setprio(0); barrier}
//    (T3-minimum phase interleave + T5 setprio; stage issue spread A/B).
//  - tile boundary keeps proven __syncthreads() drain (dbuf-2: counted vmcnt
//    across boundary is unsafe since every half is live for the whole tile).
//  - geometry & math unchanged from verified R2 (256x256, BK=128, XOR swizzle
//    on global source + ds_read addr, linear LDS dest).

#define MDIM 8192
#define KDIM 4096
#define NDIM 4096

#define BM 256
#define BN 256
#define BK 128
#define NT (KDIM / BK)  // 32 K-steps

typedef int v4i  __attribute__((ext_vector_type(4)));
typedef int v16i __attribute__((ext_vector_type(16)));

__device__ __forceinline__ void load_lds_16(const void* g, void* l) {
  __builtin_amdgcn_global_load_lds((const __attribute__((address_space(1))) void*)g,
                                   (__attribute__((address_space(3))) void*)l,
                                   16, 0, 0);
}

// ---------------- fused prep: per-token quant (blocks 0..M-1) + weight repack ----
extern "C" __global__ __launch_bounds__(256)
void qlin_prep(const float* __restrict__ x, int8_t* __restrict__ xq,
               float* __restrict__ xs, const int* __restrict__ w32,
               int8_t* __restrict__ w8) {
  const int t = threadIdx.x;
  if (blockIdx.x >= MDIM) {
    const size_t idx = (size_t)(blockIdx.x - MDIM) * 256 + t;
    const int4 w = ((const int4*)w32)[idx];
    ((int*)w8)[idx] = (w.x & 0xff) | ((w.y & 0xff) << 8) |
                      ((w.z & 0xff) << 16) | ((w.w & 0xff) << 24);
    return;
  }
  const int row = blockIdx.x;
  const float4* xr = (const float4*)(x + (size_t)row * KDIM);
  float4 v[4];
  float amax = 0.f;
#pragma unroll
  for (int i = 0; i < 4; ++i) {
    v[i] = xr[t + 256 * i];
    amax = fmaxf(amax, fmaxf(fmaxf(fabsf(v[i].x), fabsf(v[i].y)),
                             fmaxf(fabsf(v[i].z), fabsf(v[i].w))));
  }
#pragma unroll
  for (int off = 32; off > 0; off >>= 1)
    amax = fmaxf(amax, __shfl_xor(amax, off, 64));
  __shared__ float smax[4];
  if ((t & 63) == 0) smax[t >> 6] = amax;
  __syncthreads();
  amax = fmaxf(fmaxf(smax[0], smax[1]), fmaxf(smax[2], smax[3]));
  const float scale = fmaxf(amax, 1e-7f) / 127.0f;  // stored scale: exact ref math
  const float inv   = 1.0f / scale;
  if (t == 0) xs[row] = scale;
  int* outp = (int*)(xq + (size_t)row * KDIM);
#pragma unroll
  for (int i = 0; i < 4; ++i) {
    int q0 = (int)rintf(v[i].x * inv);
    int q1 = (int)rintf(v[i].y * inv);
    int q2 = (int)rintf(v[i].z * inv);
    int q3 = (int)rintf(v[i].w * inv);
    q0 = min(127, max(-128, q0));
    q1 = min(127, max(-128, q1));
    q2 = min(127, max(-128, q2));
    q3 = min(127, max(-128, q3));
    outp[t + 256 * i] = (q0 & 0xff) | ((q1 & 0xff) << 8) |
                        ((q2 & 0xff) << 16) | ((q3 & 0xff) << 24);
  }
}

// ---------------- int8 GEMM, 256x256 tile, BK=128, 8 waves, 2-subphase dbuf ----
// A = xq [M,K] row-major; B = w8 [N,K] row-major (K-contiguous).
// Wave (wr,wc): wr=wave>>2 owns rows wr*128..+128; wc=wave&3 owns cols wc*64..+64.
// LDS tile [row][128B]; physical 16B-chunk c holds logical chunk c^(row&7).
extern "C" __global__ __launch_bounds__(512, 2)
void qlin_gemm(const int8_t* __restrict__ Aq, const int8_t* __restrict__ Bq,
               const float* __restrict__ xs, const float* __restrict__ ws,
               const float* __restrict__ bias, float* __restrict__ out) {
  __shared__ int8_t As[2][BM * BK];  // 2 x 32 KB
  __shared__ int8_t Bs[2][BN * BK];  // 2 x 32 KB
  const int tid  = threadIdx.x;
  const int lane = tid & 63;
  const int wave = tid >> 6;   // 0..7
  const int wr   = wave >> 2;  // 0..1  (128-row half)
  const int wc   = wave & 3;   // 0..3  (64-col quarter)

  const int m0 = blockIdx.y * BM;
  const int n0 = blockIdx.x * BN;

  const int8_t* Ab = Aq + (size_t)m0 * KDIM;
  const int8_t* Bb = Bq + (size_t)n0 * KDIM;

  // staging map: instruction `it` covers chunk-index q = (wave*4+it)*64 + lane,
  // q in [0,2048): 256 rows x 8 chunks.  row=q>>3, c=q&7.
  // LDS dst = q*16 (linear, wave-uniform base + lane*16).
  // Global src K-chunk = c ^ (row&7)  [XOR swizzle applied at the source].
  int srow[4], scsw[4], sdst[4];
#pragma unroll
  for (int it = 0; it < 4; ++it) {
    const int q  = (wave * 4 + it) * 64 + lane;
    const int rr = q >> 3;
    const int c  = q & 7;
    srow[it] = rr;
    scsw[it] = ((c ^ (rr & 7)) << 4);
    sdst[it] = q * 16;
  }

  // fragment-read LDS byte offsets: logical 16B-chunk kc = ks*2 + hi
  const int r  = lane & 31;
  const int hi = lane >> 5;
  const int rx = r & 7;
  int aoff[4][4], boff[2][4];
#pragma unroll
  for (int ks = 0; ks < 4; ++ks) {
    const int kphys = ((ks * 2 + hi) ^ rx) << 4;
#pragma unroll
    for (int i = 0; i < 4; ++i)
      aoff[i][ks] = (wr * 128 + i * 32 + r) * BK + kphys;
#pragma unroll
    for (int j = 0; j < 2; ++j)
      boff[j][ks] = (wc * 64 + j * 32 + r) * BK + kphys;
  }

  v16i acc[4][2];
#pragma unroll
  for (int i = 0; i < 4; ++i)
#pragma unroll
    for (int j = 0; j < 2; ++j)
#pragma unroll
      for (int rg = 0; rg < 16; ++rg) acc[i][j][rg] = 0;

  auto STAGE_A = [&](int k0, int buf) {
#pragma unroll
    for (int it = 0; it < 4; ++it)
      load_lds_16(Ab + (size_t)srow[it] * KDIM + (k0 + scsw[it]), &As[buf][sdst[it]]);
  };
  auto STAGE_B = [&](int k0, int buf) {
#pragma unroll
    for (int it = 0; it < 4; ++it)
      load_lds_16(Bb + (size_t)srow[it] * KDIM + (k0 + scsw[it]), &Bs[buf][sdst[it]]);
  };

  STAGE_A(0, 0);
  STAGE_B(0, 0);
  __syncthreads();  // implicit vmcnt(0) drain + barrier -> buf0 ready

  int buf = 0;
  for (int t = 0; t < NT; ++t) {
    const bool pf = (t + 1 < NT);

    // ---- sub-phase 1: ks 0,1 ----
    {
      v4i a[4][2], b[2][2];
#pragma unroll
      for (int ks = 0; ks < 2; ++ks) {
#pragma unroll
        for (int i = 0; i < 4; ++i) a[i][ks] = *(const v4i*)(&As[buf][aoff[i][ks]]);
#pragma unroll
        for (int j = 0; j < 2; ++j) b[j][ks] = *(const v4i*)(&Bs[buf][boff[j][ks]]);
      }
      if (pf) STAGE_A((t + 1) * BK, buf ^ 1);  // in flight under MFMAs
      __builtin_amdgcn_s_barrier();            // converge waves (no drain)
      __builtin_amdgcn_s_setprio(1);
#pragma unroll
      for (int ks = 0; ks < 2; ++ks)
#pragma unroll
        for (int i = 0; i < 4; ++i)
#pragma unroll
          for (int j = 0; j < 2; ++j)
            acc[i][j] = __builtin_amdgcn_mfma_i32_32x32x32_i8(a[i][ks], b[j][ks],
                                                              acc[i][j], 0, 0, 0);
      __builtin_amdgcn_s_setprio(0);
    }
    __builtin_amdgcn_s_barrier();

    // ---- sub-phase 2: ks 2,3 ----
    {
      v4i a[4][2], b[2][2];
#pragma unroll
      for (int ks = 0; ks < 2; ++ks) {
#pragma unroll
        for (int i = 0; i < 4; ++i) a[i][ks] = *(const v4i*)(&As[buf][aoff[i][ks + 2]]);
#pragma unroll
        for (int j = 0; j < 2; ++j) b[j][ks] = *(const v4i*)(&Bs[buf][boff[j][ks + 2]]);
      }
      if (pf) STAGE_B((t + 1) * BK, buf ^ 1);
      __builtin_amdgcn_s_barrier();
      __builtin_amdgcn_s_setprio(1);
#pragma unroll
      for (int ks = 0; ks < 2; ++ks)
#pragma unroll
        for (int i = 0; i < 4; ++i)
#pragma unroll
          for (int j = 0; j < 2; ++j)
            acc[i][j] = __builtin_amdgcn_mfma_i32_32x32x32_i8(a[i][ks], b[j][ks],
                                                              acc[i][j], 0, 0, 0);
      __builtin_amdgcn_s_setprio(0);
    }

    __syncthreads();  // tile boundary: vmcnt(0)+lgkmcnt(0)+barrier (proven safe)
    buf ^= 1;
  }

  // epilogue: C/D layout col=lane&31, row=(reg&3)+8*(reg>>2)+4*(lane>>5)
  const int col = lane & 31;
  const int rb  = hi * 4;
#pragma unroll
  for (int j = 0; j < 2; ++j) {
    const int gc = n0 + wc * 64 + j * 32 + col;
    const float wsv = ws[gc];
    const float bv  = bias[gc];
#pragma unroll
    for (int i = 0; i < 4; ++i) {
      const int grb = m0 + wr * 128 + i * 32 + rb;
#pragma unroll
      for (int reg = 0; reg < 16; ++reg) {
        const int gr = grb + (reg & 3) + 8 * (reg >> 2);
        float t2 = (float)acc[i][j][reg] * xs[gr];  // (acc * x_scale)
        t2 = t2 * wsv + bv;                         // * w_scale + bias
        out[(size_t)gr * NDIM + gc] = __half2float(__float2half(t2));
      }
    }
  }
}

extern "C" void kernel_launch(void* const* d_in, const int* in_sizes, int n_in,
                              void* d_out, int out_size, void* d_ws, size_t ws_size,
                              hipStream_t stream) {
  const float* x      = (const float*)d_in[0];
  const int*   wq32   = (const int*)d_in[1];    // int8 promoted to int32 by harness
  const float* wscale = (const float*)d_in[2];
  const float* bias   = (const float*)d_in[3];  // fp16 promoted to fp32 by harness
  float*       out    = (float*)d_out;

  int8_t* xq = (int8_t*)d_ws;                                    // M*K = 32 MiB
  int8_t* w8 = (int8_t*)d_ws + (size_t)MDIM * KDIM;              // N*K = 16 MiB
  float*  xs = (float*)((int8_t*)d_ws + (size_t)MDIM * KDIM + (size_t)NDIM * KDIM);

  qlin_prep<<<MDIM + (NDIM * KDIM / 4) / 256, 256, 0, stream>>>(x, xq, xs, wq32, w8);
  qlin_gemm<<<dim3(NDIM / BN, MDIM / BM), 512, 0, stream>>>(xq, w8, xs, wscale, bias, out);
}